// Round 2
// baseline (422.882 us; speedup 1.0000x reference)
//
#include <hip/hip_runtime.h>
#include <stdint.h>

typedef float  f32x4 __attribute__((ext_vector_type(4)));
typedef short  s16x8 __attribute__((ext_vector_type(8)));
typedef short  s16x4 __attribute__((ext_vector_type(4)));
typedef unsigned int uint32;

#define B_ 16
#define N_ 256
#define T_ 64
#define F_ 128
#define KT 32
#define NT 8   /* K tiles: 8*32 = 256 */

// LDS layout (bytes). 16x16 bf16 subtiles (512B), inter-subtile stride 544.
// X is a 2-tile double buffer; W one 256x32 tile; E/J id staging.
#define BLKSTR 544
#define X_TILE_STR (16 * BLKSTR)          /* 8704 per k-tile */
#define X_OFF 0
#define W_OFF (2 * X_TILE_STR)            /* 17408 */
#define E_OFF (W_OFF + 32 * BLKSTR)       /* 34816 */
#define J_OFF (E_OFF + N_ * 4)            /* 35840 */
#define LDS_SZ (J_OFF + N_)               /* 36096 -> 4 blocks/CU */

// epilogue scratch (reuses X+W region): 64 rows x 132 f32 (528B stride)
#define SCR_STRIDE 132

#define TRREAD(dst, addr) \
  asm volatile("ds_read_b64_tr_b16 %0, %1" : "=v"(dst) : "v"(addr))

#define LGKM_FENCE() asm volatile("s_waitcnt lgkmcnt(0)" ::: "memory")
#define BAR()                                    \
  do {                                           \
    LGKM_FENCE();                                \
    __builtin_amdgcn_s_barrier();                \
    asm volatile("" ::: "memory");               \
  } while (0)

__device__ __forceinline__ unsigned short f2bf(float f) {
  union { float f; unsigned int u; } v; v.f = f;
  unsigned int u = v.u;
  return (unsigned short)((u + 0x7fffu + ((u >> 16) & 1u)) >> 16);
}

// fwTb[c][l] = bf16(full_weight[l][c])  (256x256, lives in d_ws, L2-resident)
__global__ void wtrans_kernel(const float* __restrict__ fw,
                              unsigned short* __restrict__ fwTb) {
  int c = blockIdx.x;
  int l = threadIdx.x;
  fwTb[c * N_ + l] = f2bf(fw[l * N_ + c]);
}

__global__ __launch_bounds__(512, 8) void fused_kernel(
    const float* __restrict__ x,
    const int* __restrict__ entry,
    const int* __restrict__ job,
    const unsigned short* __restrict__ fwTb,
    float* __restrict__ out) {
  __shared__ __align__(16) char smem[LDS_SZ];
  const uint32 lds_u = (uint32)(uintptr_t)(&smem[0]);

  const int tid = threadIdx.x;
  const int bid = blockIdx.x;
  const int b = bid >> 6;
  const int t = bid & 63;

  // ---- prologue: stage entry ids (i32) and job ids (u8) for all k ----
  if (tid < N_) {
    int idx = (b * N_ + tid) * T_ + t;
    *(int*)(smem + E_OFF + 4 * tid) = entry[idx];
    smem[J_OFF + tid] = (char)job[idx];
  }

  // X staging thread mapping: lane-contig in f for coalesced HBM reads
  const int xk  = tid >> 4;          // 0..31 (k offset within tile)
  const int xf0 = (tid & 15) << 3;   // 0,8,...,120
  const uint32 xdst_in = (uint32)((((xk >> 4) * 8 + (xf0 >> 4)) * BLKSTR) +
                                  ((xk & 15) * 32) + ((xf0 & 15) * 2));

  // stage X tile 0 (f32 -> bf16, into [k16][f16] subtiles) into buf 0
  {
    const float* src = x + ((b * N_ + xk) * T_ + t) * F_ + xf0;
    f32x4 r0 = *(const f32x4*)(src);
    f32x4 r1 = *(const f32x4*)(src + 4);
    s16x8 pk;
#pragma unroll
    for (int i = 0; i < 4; ++i) {
      pk[i]     = (short)f2bf(r0[i]);
      pk[i + 4] = (short)f2bf(r1[i]);
    }
    *(s16x8*)(smem + X_OFF + xdst_in) = pk;
  }
  BAR();

  const int lane = tid & 63;
  const int wid  = tid >> 6;
  const int wl   = wid & 3;   // wave's 64-l tile
  const int wf   = wid >> 2;  // wave's 64-f tile

  f32x4 acc[4][4];
#pragma unroll
  for (int i = 0; i < 4; ++i)
#pragma unroll
    for (int j = 0; j < 4; ++j) acc[i][j] = (f32x4){0.f, 0.f, 0.f, 0.f};

  for (int kt = 0; kt < NT; ++kt) {
    // ---- W build (tile kt): Wm[l,k] = fwTb[e_k][l] * (j_l==j_k!=0) ----
    {
      const int wk  = tid & 31;   // k offset in tile
      const int wlg = tid >> 5;   // 0..15 l-block
      const int k   = kt * KT + wk;
      const int ev  = *(const int*)(smem + E_OFF + 4 * k);
      const unsigned char jk = (unsigned char)smem[J_OFF + k];
      const unsigned short* wrow = fwTb + ev * N_;
      const uint32 kin = (uint32)((wk & 15) * 32);
      const int kb = (wk >> 4) & 1;
#pragma unroll
      for (int it = 0; it < 2; ++it) {
        const int l0 = wlg * 16 + it * 8;
        s16x8 wv = *(const s16x8*)(wrow + l0);                 // 16B from L2
        uint64_t jl8 = *(const uint64_t*)(smem + J_OFF + l0);  // 8 job bytes
        s16x8 m;
#pragma unroll
        for (int i = 0; i < 8; ++i) {
          unsigned char jl = (unsigned char)(jl8 >> (8 * i));
          m[i] = (jk != 0 && jl == jk) ? wv[i] : (short)0;
        }
        char* dst = smem + W_OFF + ((kb * 16 + wlg) * BLKSTR) + kin + it * 16;
        *(s16x8*)dst = m;
      }
    }

    // ---- issue X global loads for tile kt+1 (stay in flight over barrier) --
    f32x4 p0, p1;
    if (kt + 1 < NT) {
      const float* src = x + ((b * N_ + (kt + 1) * KT + xk) * T_ + t) * F_ + xf0;
      p0 = *(const f32x4*)(src);
      p1 = *(const f32x4*)(src + 4);
    }

    BAR();  // lgkm-only drain: W tile + X[cur] visible; X loads still in flight

    // ---- MFMA: 64l x 64f per wave, K=32, X from buf (kt&1) ----
    {
      s16x4 ah[4][2], bh[4][2];
      const uint32 wbase = lds_u + W_OFF + (uint32)(lane * 8);
      const uint32 xbase =
          lds_u + X_OFF + (uint32)((kt & 1) * X_TILE_STR + lane * 8);
#pragma unroll
      for (int li = 0; li < 4; ++li) {
        const uint32 a0 = wbase + (uint32)(((0 * 16) + (wl * 4 + li)) * BLKSTR);
        const uint32 a1 = wbase + (uint32)(((1 * 16) + (wl * 4 + li)) * BLKSTR);
        TRREAD(ah[li][0], a0);
        TRREAD(ah[li][1], a1);
      }
#pragma unroll
      for (int fi = 0; fi < 4; ++fi) {
        const uint32 b0 = xbase + (uint32)(((0 * 8) + (wf * 4 + fi)) * BLKSTR);
        const uint32 b1 = xbase + (uint32)(((1 * 8) + (wf * 4 + fi)) * BLKSTR);
        TRREAD(bh[fi][0], b0);
        TRREAD(bh[fi][1], b1);
      }
      LGKM_FENCE();
      __builtin_amdgcn_sched_barrier(0);  // rule #18: keep MFMAs below the wait
#pragma unroll
      for (int li = 0; li < 4; ++li) {
        s16x8 af = __builtin_shufflevector(ah[li][0], ah[li][1],
                                           0, 1, 2, 3, 4, 5, 6, 7);
#pragma unroll
        for (int fi = 0; fi < 4; ++fi) {
          s16x8 bf = __builtin_shufflevector(bh[fi][0], bh[fi][1],
                                             0, 1, 2, 3, 4, 5, 6, 7);
          acc[li][fi] =
              __builtin_amdgcn_mfma_f32_16x16x32_bf16(af, bf, acc[li][fi], 0, 0, 0);
        }
      }
    }

    // ---- convert+write X tile kt+1 into buf (kt+1)&1 (vmcnt wait lands here)
    if (kt + 1 < NT) {
      s16x8 pk;
#pragma unroll
      for (int i = 0; i < 4; ++i) {
        pk[i]     = (short)f2bf(p0[i]);
        pk[i + 4] = (short)f2bf(p1[i]);
      }
      *(s16x8*)(smem + X_OFF + ((kt + 1) & 1) * X_TILE_STR + xdst_in) = pk;
    }

    BAR();  // X tile kt+1 visible; W buffer free for next build
  }

  // ---- epilogue: out = x + relu(y), via LDS transpose for coalesced I/O ----
  // Reuse X+W region (34816 B >= 64*132*4 = 33792 B) as f32 scratch.
  float* scrf = (float*)smem;
  const int g4   = (lane >> 4) * 4;
  const int fcol = lane & 15;
  const int erow = tid >> 3;          // 0..63
  const int ef0  = (tid & 7) * 16;    // 0,16,...,112
#pragma unroll
  for (int li = 0; li < 4; ++li) {
    // scatter this chunk's relu(acc) into scratch: row = wl*16+g4+r
#pragma unroll
    for (int fi = 0; fi < 4; ++fi) {
#pragma unroll
      for (int r = 0; r < 4; ++r) {
        float y = acc[li][fi][r];
        y = y > 0.f ? y : 0.f;
        scrf[(wl * 16 + g4 + r) * SCR_STRIDE + wf * 64 + fi * 16 + fcol] = y;
      }
    }
    BAR();
    // coalesced read-back: l = (erow>>4)*64 + li*16 + (erow&15)
    const int l = (erow >> 4) * 64 + li * 16 + (erow & 15);
    const float* xr = x + ((b * N_ + l) * T_ + t) * F_ + ef0;
    float* op = out + ((b * N_ + l) * T_ + t) * F_ + ef0;
#pragma unroll
    for (int q = 0; q < 4; ++q) {
      f32x4 xv = *(const f32x4*)(xr + 4 * q);
      f32x4 yv = *(const f32x4*)(scrf + erow * SCR_STRIDE + ef0 + 4 * q);
      f32x4 ov = xv + yv;
      *(f32x4*)(op + 4 * q) = ov;
    }
    if (li < 3) BAR();  // protect next chunk's scratch writes
  }
}

extern "C" void kernel_launch(void* const* d_in, const int* in_sizes, int n_in,
                              void* d_out, int out_size, void* d_ws,
                              size_t ws_size, hipStream_t stream) {
  (void)in_sizes; (void)n_in; (void)out_size; (void)ws_size;
  const float* x     = (const float*)d_in[0];
  const int*   entry = (const int*)d_in[1];
  const int*   job   = (const int*)d_in[2];
  // d_in[3] rackid unused; d_in[5..7] bias/gamma/beta dead in reference math
  const float* fw    = (const float*)d_in[4];
  unsigned short* fwTb = (unsigned short*)d_ws;  // 128 KB scratch

  hipLaunchKernelGGL(wtrans_kernel, dim3(N_), dim3(N_), 0, stream, fw, fwTb);
  hipLaunchKernelGGL(fused_kernel, dim3(B_ * T_), dim3(512), 0, stream,
                     x, entry, job, (const unsigned short*)fwTb, (float*)d_out);
}

// Round 3
// 121.560 us; speedup vs baseline: 3.4788x; 3.4788x over previous
//
#include <hip/hip_runtime.h>
#include <stdint.h>

typedef float  f32x4 __attribute__((ext_vector_type(4)));
typedef short  s16x8 __attribute__((ext_vector_type(8)));
typedef short  s16x4 __attribute__((ext_vector_type(4)));
typedef unsigned int uint32;

#define B_ 16
#define N_ 256
#define T_ 64
#define F_ 128
#define KT 32
#define NT 8   /* K tiles: 8*32 = 256 */
#define NL 128 /* l rows per block (l-half) */

// LDS layout (bytes). 16x16 bf16 subtiles (512B), inter-subtile stride 544.
// X: 2-tile double buffer (32k x 128f each). W: one 128l x 32k tile.
#define BLKSTR 544
#define X_TILE_STR (16 * BLKSTR)          /* 8704 per k-tile */
#define X_OFF 0
#define W_OFF (2 * X_TILE_STR)            /* 17408 */
#define E_OFF (W_OFF + 16 * BLKSTR)       /* 26112 */
#define J_OFF (E_OFF + N_ * 4)            /* 27136 */
#define LDS_SZ (J_OFF + N_)               /* 27392 -> 5 blocks/CU by LDS */

// epilogue scratch (reuses X region): 32 rows x 132 f32 = 16896 B
#define SCR_STRIDE 132

#define TRREAD(dst, addr) \
  asm volatile("ds_read_b64_tr_b16 %0, %1" : "=v"(dst) : "v"(addr))

#define LGKM_FENCE() asm volatile("s_waitcnt lgkmcnt(0)" ::: "memory")
#define BAR()                                    \
  do {                                           \
    LGKM_FENCE();                                \
    __builtin_amdgcn_s_barrier();                \
    asm volatile("" ::: "memory");               \
  } while (0)

__device__ __forceinline__ unsigned short f2bf(float f) {
  union { float f; unsigned int u; } v; v.f = f;
  unsigned int u = v.u;
  return (unsigned short)((u + 0x7fffu + ((u >> 16) & 1u)) >> 16);
}

// fwTb[c][l] = bf16(full_weight[l][c])  (256x256, lives in d_ws, L2-resident)
__global__ void wtrans_kernel(const float* __restrict__ fw,
                              unsigned short* __restrict__ fwTb) {
  int c = blockIdx.x;
  int l = threadIdx.x;
  fwTb[c * N_ + l] = f2bf(fw[l * N_ + c]);
}

__global__ __launch_bounds__(256, 4) void fused_kernel(
    const float* __restrict__ x,
    const int* __restrict__ entry,
    const int* __restrict__ job,
    const unsigned short* __restrict__ fwTb,
    float* __restrict__ out) {
  __shared__ __align__(16) char smem[LDS_SZ];
  const uint32 lds_u = (uint32)(uintptr_t)(&smem[0]);

  const int tid = threadIdx.x;
  const int bid = blockIdx.x;
  const int b  = bid >> 7;
  const int t  = (bid >> 1) & 63;
  const int lh = bid & 1;            // l-half: rows [lh*128, lh*128+128)

  // ---- prologue: stage entry ids (i32) and job ids (u8) for all 256 k ----
  {
    int idx = (b * N_ + tid) * T_ + t;
    *(int*)(smem + E_OFF + 4 * tid) = entry[idx];
    smem[J_OFF + tid] = (char)job[idx];
  }

  // X staging thread mapping: each thread stages k = xk and xk+16 at f-span xf0
  const int xk  = tid >> 4;          // 0..15
  const int xf0 = (tid & 15) << 3;   // 0,8,...,120
  const uint32 xdst_in = (uint32)(((xf0 >> 4) * BLKSTR) +
                                  ((xk & 15) * 32) + ((xf0 & 15) * 2));

  // stage X tile 0 (f32 -> bf16, [k16][f16] subtiles) into buf 0
  {
    const float* s0 = x + ((b * N_ + xk) * T_ + t) * F_ + xf0;
    const float* s1 = x + ((b * N_ + xk + 16) * T_ + t) * F_ + xf0;
    f32x4 r0 = *(const f32x4*)(s0);
    f32x4 r1 = *(const f32x4*)(s0 + 4);
    f32x4 r2 = *(const f32x4*)(s1);
    f32x4 r3 = *(const f32x4*)(s1 + 4);
    s16x8 pk0, pk1;
#pragma unroll
    for (int i = 0; i < 4; ++i) {
      pk0[i]     = (short)f2bf(r0[i]);
      pk0[i + 4] = (short)f2bf(r1[i]);
      pk1[i]     = (short)f2bf(r2[i]);
      pk1[i + 4] = (short)f2bf(r3[i]);
    }
    *(s16x8*)(smem + X_OFF + xdst_in) = pk0;
    *(s16x8*)(smem + X_OFF + xdst_in + 8 * BLKSTR) = pk1;
  }
  BAR();

  const int lane = tid & 63;
  const int wid  = tid >> 6;  // 0..3
  const int wl   = wid & 1;   // wave's 64-l sub-tile
  const int wf   = wid >> 1;  // wave's 64-f sub-tile

  f32x4 acc[4][4];
#pragma unroll
  for (int i = 0; i < 4; ++i)
#pragma unroll
    for (int j = 0; j < 4; ++j) acc[i][j] = (f32x4){0.f, 0.f, 0.f, 0.f};

  for (int kt = 0; kt < NT; ++kt) {
    // ---- W build (tile kt): Wm[l,k] = fwTb[e_k][l] * (j_l==j_k!=0) ----
    {
      const int wk  = tid & 31;   // k offset in tile
      const int wlg = tid >> 5;   // 0..7 (16-l groups within this half)
      const int k   = kt * KT + wk;
      const int ev  = *(const int*)(smem + E_OFF + 4 * k);
      const unsigned char jk = (unsigned char)smem[J_OFF + k];
      const unsigned short* wrow = fwTb + ev * N_ + lh * NL;
      const uint32 kin = (uint32)((wk & 15) * 32);
      const int kb = wk >> 4;
#pragma unroll
      for (int it = 0; it < 2; ++it) {
        const int lg8 = wlg * 16 + it * 8;                     // local l
        s16x8 wv = *(const s16x8*)(wrow + lg8);                // 16B from L2
        uint64_t jl8 =
            *(const uint64_t*)(smem + J_OFF + lh * NL + lg8);  // 8 job bytes
        s16x8 m;
#pragma unroll
        for (int i = 0; i < 8; ++i) {
          unsigned char jl = (unsigned char)(jl8 >> (8 * i));
          m[i] = (jk != 0 && jl == jk) ? wv[i] : (short)0;
        }
        char* dst = smem + W_OFF + ((kb * 8 + wlg) * BLKSTR) + kin + it * 16;
        *(s16x8*)dst = m;
      }
    }

    // ---- issue X global loads for tile kt+1 (stay in flight over barrier) --
    f32x4 p0, p1, p2, p3;
    if (kt + 1 < NT) {
      const int kbase = (kt + 1) * KT;
      const float* s0 = x + ((b * N_ + kbase + xk) * T_ + t) * F_ + xf0;
      const float* s1 = x + ((b * N_ + kbase + xk + 16) * T_ + t) * F_ + xf0;
      p0 = *(const f32x4*)(s0);
      p1 = *(const f32x4*)(s0 + 4);
      p2 = *(const f32x4*)(s1);
      p3 = *(const f32x4*)(s1 + 4);
    }

    BAR();  // lgkm-only drain: W tile + X[cur] visible; X loads still in flight

    // ---- MFMA: 64l x 64f per wave, K=32, X from buf (kt&1) ----
    {
      s16x4 ah[4][2], bh[4][2];
      const uint32 wbase = lds_u + W_OFF + (uint32)(lane * 8);
      const uint32 xbase =
          lds_u + X_OFF + (uint32)((kt & 1) * X_TILE_STR + lane * 8);
#pragma unroll
      for (int li = 0; li < 4; ++li) {
        const uint32 a0 = wbase + (uint32)(((0 * 8) + (wl * 4 + li)) * BLKSTR);
        const uint32 a1 = wbase + (uint32)(((1 * 8) + (wl * 4 + li)) * BLKSTR);
        TRREAD(ah[li][0], a0);
        TRREAD(ah[li][1], a1);
      }
#pragma unroll
      for (int fi = 0; fi < 4; ++fi) {
        const uint32 b0 = xbase + (uint32)(((0 * 8) + (wf * 4 + fi)) * BLKSTR);
        const uint32 b1 = xbase + (uint32)(((1 * 8) + (wf * 4 + fi)) * BLKSTR);
        TRREAD(bh[fi][0], b0);
        TRREAD(bh[fi][1], b1);
      }
      LGKM_FENCE();
      __builtin_amdgcn_sched_barrier(0);  // rule #18: keep MFMAs below the wait
#pragma unroll
      for (int li = 0; li < 4; ++li) {
        s16x8 af = __builtin_shufflevector(ah[li][0], ah[li][1],
                                           0, 1, 2, 3, 4, 5, 6, 7);
#pragma unroll
        for (int fi = 0; fi < 4; ++fi) {
          s16x8 bf = __builtin_shufflevector(bh[fi][0], bh[fi][1],
                                             0, 1, 2, 3, 4, 5, 6, 7);
          acc[li][fi] =
              __builtin_amdgcn_mfma_f32_16x16x32_bf16(af, bf, acc[li][fi], 0, 0, 0);
        }
      }
    }

    // ---- convert+write X tile kt+1 into buf (kt+1)&1 (vmcnt wait lands here)
    if (kt + 1 < NT) {
      s16x8 pk0, pk1;
#pragma unroll
      for (int i = 0; i < 4; ++i) {
        pk0[i]     = (short)f2bf(p0[i]);
        pk0[i + 4] = (short)f2bf(p1[i]);
        pk1[i]     = (short)f2bf(p2[i]);
        pk1[i + 4] = (short)f2bf(p3[i]);
      }
      char* base = smem + X_OFF + ((kt + 1) & 1) * X_TILE_STR + xdst_in;
      *(s16x8*)(base) = pk0;
      *(s16x8*)(base + 8 * BLKSTR) = pk1;
    }

    BAR();  // X tile kt+1 visible; W buffer free for next build
  }

  // ---- epilogue: out = x + relu(y), LDS-transpose per 32-row chunk ----
  // Scratch (32 x 132 f32 = 16896 B) reuses the X region.
  float* scrf = (float*)smem;
  const int g4   = (lane >> 4) * 4;
  const int fcol = lane & 15;
  const int erow = tid >> 3;          // 0..31
  const int ef0  = (tid & 7) * 16;    // 0,16,...,112
#pragma unroll
  for (int c = 0; c < 4; ++c) {
    if (wl == (c >> 1)) {             // wave-uniform
      const int li0 = (c & 1) * 2;
#pragma unroll
      for (int q = 0; q < 2; ++q) {
        const int lrb = q * 16 + g4;
#pragma unroll
        for (int fi = 0; fi < 4; ++fi) {
#pragma unroll
          for (int r = 0; r < 4; ++r) {
            float y = acc[li0 + q][fi][r];
            y = y > 0.f ? y : 0.f;
            scrf[(lrb + r) * SCR_STRIDE + wf * 64 + fi * 16 + fcol] = y;
          }
        }
      }
    }
    BAR();
    const int l = lh * NL + c * 32 + erow;
    const float* xr = x + ((b * N_ + l) * T_ + t) * F_ + ef0;
    float* op = out + ((b * N_ + l) * T_ + t) * F_ + ef0;
#pragma unroll
    for (int q = 0; q < 4; ++q) {
      f32x4 xv = *(const f32x4*)(xr + 4 * q);
      f32x4 yv = *(const f32x4*)(scrf + erow * SCR_STRIDE + ef0 + 4 * q);
      f32x4 ov = xv + yv;
      *(f32x4*)(op + 4 * q) = ov;
    }
    if (c < 3) BAR();  // protect next chunk's scratch writes
  }
}

extern "C" void kernel_launch(void* const* d_in, const int* in_sizes, int n_in,
                              void* d_out, int out_size, void* d_ws,
                              size_t ws_size, hipStream_t stream) {
  (void)in_sizes; (void)n_in; (void)out_size; (void)ws_size;
  const float* x     = (const float*)d_in[0];
  const int*   entry = (const int*)d_in[1];
  const int*   job   = (const int*)d_in[2];
  // d_in[3] rackid unused; d_in[5..7] bias/gamma/beta dead in reference math
  const float* fw    = (const float*)d_in[4];
  unsigned short* fwTb = (unsigned short*)d_ws;  // 128 KB scratch

  hipLaunchKernelGGL(wtrans_kernel, dim3(N_), dim3(N_), 0, stream, fw, fwTb);
  hipLaunchKernelGGL(fused_kernel, dim3(B_ * T_ * 2), dim3(256), 0, stream,
                     x, entry, job, (const unsigned short*)fwTb, (float*)d_out);
}

// Round 4
// 76.878 us; speedup vs baseline: 5.5007x; 1.5812x over previous
//
#include <hip/hip_runtime.h>
#include <stdint.h>

typedef float  f32x4 __attribute__((ext_vector_type(4)));
typedef short  s16x8 __attribute__((ext_vector_type(8)));
typedef short  s16x4 __attribute__((ext_vector_type(4)));
typedef unsigned int uint32;

#define B_ 16
#define N_ 256
#define T_ 64
#define F_ 128
#define KT 32
#define NT 8   /* K tiles: 8*32 = 256 */

// LDS layout (bytes). 16x16 bf16 subtiles (512B), inter-subtile stride 544.
// X: all 8 k-tiles resident (residual source, read-only after prologue).
// W: 2-tile double buffer (256l x 32k each).
#define BLKSTR 544
#define X_TILE_STR (16 * BLKSTR)            /* 8704 per k-tile */
#define X_OFF 0
#define W_OFF (NT * X_TILE_STR)             /* 69632 */
#define W_BUF_STR (32 * BLKSTR)             /* 17408 per W buffer */
#define E_OFF (W_OFF + 2 * W_BUF_STR)       /* 104448 */
#define J_OFF (E_OFF + N_ * 4)              /* 105472 */
#define LDS_SZ (J_OFF + N_)                 /* 105728 -> 1 block/CU */

#define TRREAD(dst, addr) \
  asm volatile("ds_read_b64_tr_b16 %0, %1" : "=v"(dst) : "v"(addr))

#define LGKM_FENCE() asm volatile("s_waitcnt lgkmcnt(0)" ::: "memory")
#define BAR()                                    \
  do {                                           \
    LGKM_FENCE();                                \
    __builtin_amdgcn_s_barrier();                \
    asm volatile("" ::: "memory");               \
  } while (0)

__device__ __forceinline__ unsigned short f2bf(float f) {
  union { float f; unsigned int u; } v; v.f = f;
  unsigned int u = v.u;
  return (unsigned short)((u + 0x7fffu + ((u >> 16) & 1u)) >> 16);
}
__device__ __forceinline__ float bf2f(unsigned short h) {
  union { unsigned int u; float f; } v; v.u = ((unsigned int)h) << 16;
  return v.f;
}

// fwTb[c][l] = bf16(full_weight[l][c])  (256x256, lives in d_ws, L2-resident)
__global__ void wtrans_kernel(const float* __restrict__ fw,
                              unsigned short* __restrict__ fwTb) {
  int c = blockIdx.x;
  int l = threadIdx.x;
  fwTb[c * N_ + l] = f2bf(fw[l * N_ + c]);
}

__global__ __launch_bounds__(512, 2) void fused_kernel(
    const float* __restrict__ x,
    const int* __restrict__ entry,
    const int* __restrict__ job,
    const unsigned short* __restrict__ fwTb,
    float* __restrict__ out) {
  __shared__ __align__(16) char smem[LDS_SZ];
  const uint32 lds_u = (uint32)(uintptr_t)(&smem[0]);

  const int tid = threadIdx.x;
  const int bid = blockIdx.x;
  const int b = bid >> 6;
  const int t = bid & 63;

  // ---- E/J loads FIRST (oldest in vmcnt queue -> cheap partial wait) ----
  int e_val = 0, j_val = 0;
  if (tid < N_) {
    const int idx = (b * N_ + tid) * T_ + t;
    e_val = entry[idx];
    j_val = job[idx];
  }

  // ---- issue ALL X loads (8 tiles x 2 f32x4/thread; deep HBM queue) ----
  const int xk  = tid >> 4;          // 0..31 (k offset within a tile)
  const int xf0 = (tid & 15) << 3;   // 0,8,...,120
  const float* xsrc = x + ((b * N_ + xk) * T_ + t) * F_ + xf0;
#define XLD(i)                                                            \
  f32x4 q##i##a = *(const f32x4*)(xsrc + (i) * (KT * T_ * F_));           \
  f32x4 q##i##b = *(const f32x4*)(xsrc + (i) * (KT * T_ * F_) + 4);
  XLD(0) XLD(1) XLD(2) XLD(3) XLD(4) XLD(5) XLD(6) XLD(7)
#undef XLD

  if (tid < N_) {
    *(int*)(smem + E_OFF + 4 * tid) = e_val;
    smem[J_OFF + tid] = (char)j_val;
  }
  BAR();  // E/J visible (lgkm-only: X loads stay in flight)

  // ---- W(0) gather from L2 (overlaps X converts below) ----
  const int wk  = tid & 31;   // this thread's k within tile
  const int wlg = tid >> 5;   // this thread's 16-row l group (0..15)
  s16x8 gv0, gv1;
  unsigned char gjk;
  {
    const int ev = *(const int*)(smem + E_OFF + 4 * wk);
    gjk = (unsigned char)smem[J_OFF + wk];
    const unsigned short* wrow = fwTb + ev * N_ + wlg * 16;
    gv0 = *(const s16x8*)(wrow);
    gv1 = *(const s16x8*)(wrow + 8);
  }

  // job bytes of this thread's 16 l-rows: loop-invariant, hoisted
  const uint64_t jl80 = *(const uint64_t*)(smem + J_OFF + wlg * 16);
  const uint64_t jl81 = *(const uint64_t*)(smem + J_OFF + wlg * 16 + 8);

  // ---- X convert + stage, all 8 tiles ----
  const uint32 xdst_in = (uint32)((((xk >> 4) * 8 + (xf0 >> 4)) * BLKSTR) +
                                  ((xk & 15) * 32) + ((xf0 & 15) * 2));
#define XST(i)                                                            \
  {                                                                       \
    s16x8 pk;                                                             \
    _Pragma("unroll") for (int _j = 0; _j < 4; ++_j) {                    \
      pk[_j]     = (short)f2bf(q##i##a[_j]);                              \
      pk[_j + 4] = (short)f2bf(q##i##b[_j]);                              \
    }                                                                     \
    *(s16x8*)(smem + X_OFF + (i) * X_TILE_STR + xdst_in) = pk;            \
  }
  XST(0) XST(1) XST(2) XST(3) XST(4) XST(5) XST(6) XST(7)
#undef XST

  // ---- W(0) mask + write into buffer 0 ----
  const uint32 wwr_base =
      (uint32)(((wk >> 4) * 16 + wlg) * BLKSTR + (wk & 15) * 32);
  {
    s16x8 m0, m1;
#pragma unroll
    for (int i = 0; i < 8; ++i) {
      const unsigned char a0 = (unsigned char)(jl80 >> (8 * i));
      const unsigned char a1 = (unsigned char)(jl81 >> (8 * i));
      m0[i] = (gjk != 0 && a0 == gjk) ? gv0[i] : (short)0;
      m1[i] = (gjk != 0 && a1 == gjk) ? gv1[i] : (short)0;
    }
    *(s16x8*)(smem + W_OFF + wwr_base) = m0;
    *(s16x8*)(smem + W_OFF + wwr_base + 16) = m1;
  }
  BAR();  // X fully staged + W(0) ready

  const int lane = tid & 63;
  const int wid  = tid >> 6;
  const int wl   = wid & 3;   // wave's 64-l sub-tile (0..3)
  const int wf   = wid >> 2;  // wave's 64-f sub-tile (0..1)

  f32x4 acc[4][4];
#pragma unroll
  for (int i = 0; i < 4; ++i)
#pragma unroll
    for (int j = 0; j < 4; ++j) acc[i][j] = (f32x4){0.f, 0.f, 0.f, 0.f};

  for (int kt = 0; kt < NT; ++kt) {
    // ---- prefetch W gather for kt+1 into registers (L2 latency hides
    //      under the tr_read + MFMA phase below) ----
    s16x8 pv0, pv1;
    unsigned char pjk = 0;
    if (kt + 1 < NT) {
      const int k = (kt + 1) * KT + wk;
      const int ev = *(const int*)(smem + E_OFF + 4 * k);
      pjk = (unsigned char)smem[J_OFF + k];
      const unsigned short* wrow = fwTb + ev * N_ + wlg * 16;
      pv0 = *(const s16x8*)(wrow);
      pv1 = *(const s16x8*)(wrow + 8);
    }

    // ---- fragments + MFMA: W from buf (kt&1), X from resident tile kt ----
    {
      s16x4 ah[4][2], bh[4][2];
      const uint32 wbase =
          lds_u + W_OFF + (uint32)((kt & 1) * W_BUF_STR) + (uint32)(lane * 8);
      const uint32 xbase =
          lds_u + X_OFF + (uint32)(kt * X_TILE_STR) + (uint32)(lane * 8);
#pragma unroll
      for (int li = 0; li < 4; ++li) {
        TRREAD(ah[li][0], wbase + (uint32)((wl * 4 + li) * BLKSTR));
        TRREAD(ah[li][1], wbase + (uint32)((16 + wl * 4 + li) * BLKSTR));
      }
#pragma unroll
      for (int fi = 0; fi < 4; ++fi) {
        TRREAD(bh[fi][0], xbase + (uint32)((wf * 4 + fi) * BLKSTR));
        TRREAD(bh[fi][1], xbase + (uint32)((8 + wf * 4 + fi) * BLKSTR));
      }
      LGKM_FENCE();
      __builtin_amdgcn_sched_barrier(0);  // rule #18: MFMAs below the wait
#pragma unroll
      for (int li = 0; li < 4; ++li) {
        s16x8 af = __builtin_shufflevector(ah[li][0], ah[li][1],
                                           0, 1, 2, 3, 4, 5, 6, 7);
#pragma unroll
        for (int fi = 0; fi < 4; ++fi) {
          s16x8 bf = __builtin_shufflevector(bh[fi][0], bh[fi][1],
                                             0, 1, 2, 3, 4, 5, 6, 7);
          acc[li][fi] =
              __builtin_amdgcn_mfma_f32_16x16x32_bf16(af, bf, acc[li][fi], 0, 0, 0);
        }
      }
      __builtin_amdgcn_sched_barrier(0);  // keep gather-wait/mask below MFMAs
    }

    // ---- mask + write W(kt+1) into the other buffer; ONE barrier per kt ----
    if (kt + 1 < NT) {
      s16x8 m0, m1;
#pragma unroll
      for (int i = 0; i < 8; ++i) {
        const unsigned char a0 = (unsigned char)(jl80 >> (8 * i));
        const unsigned char a1 = (unsigned char)(jl81 >> (8 * i));
        m0[i] = (pjk != 0 && a0 == pjk) ? pv0[i] : (short)0;
        m1[i] = (pjk != 0 && a1 == pjk) ? pv1[i] : (short)0;
      }
      char* wb = smem + W_OFF + ((kt + 1) & 1) * W_BUF_STR + wwr_base;
      *(s16x8*)(wb) = m0;
      *(s16x8*)(wb + 16) = m1;
      BAR();  // W(kt+1) visible; all reads of buf (kt&1) already fenced
    }
  }

  // ---- epilogue: out = x + relu(y); residual from resident X LDS ----
  const int g4   = (lane >> 4) * 4;
  const int fcol = lane & 15;
#pragma unroll
  for (int li = 0; li < 4; ++li) {
    const int Lb = wl * 4 + li;  // 16-row l-block 0..15
    const uint32 rb = lds_u + X_OFF + (uint32)((Lb >> 1) * X_TILE_STR +
                       ((Lb & 1) * 8) * BLKSTR + lane * 8);
    s16x4 xr[4];
#pragma unroll
    for (int fi = 0; fi < 4; ++fi) {
      TRREAD(xr[fi], rb + (uint32)((wf * 4 + fi) * BLKSTR));
    }
    LGKM_FENCE();
    __builtin_amdgcn_sched_barrier(0);
    const int l0 = Lb * 16 + g4;
#pragma unroll
    for (int fi = 0; fi < 4; ++fi) {
      const int f = (wf * 4 + fi) * 16 + fcol;
      float* op = out + ((b * N_ + l0) * T_ + t) * F_ + f;
#pragma unroll
      for (int r = 0; r < 4; ++r) {
        float y = acc[li][fi][r];
        y = y > 0.f ? y : 0.f;
        op[r * (T_ * F_)] = bf2f((unsigned short)xr[fi][r]) + y;
      }
    }
  }
}

extern "C" void kernel_launch(void* const* d_in, const int* in_sizes, int n_in,
                              void* d_out, int out_size, void* d_ws,
                              size_t ws_size, hipStream_t stream) {
  (void)in_sizes; (void)n_in; (void)out_size; (void)ws_size;
  const float* x     = (const float*)d_in[0];
  const int*   entry = (const int*)d_in[1];
  const int*   job   = (const int*)d_in[2];
  // d_in[3] rackid unused; d_in[5..7] bias/gamma/beta dead in reference math
  const float* fw    = (const float*)d_in[4];
  unsigned short* fwTb = (unsigned short*)d_ws;  // 128 KB scratch

  hipLaunchKernelGGL(wtrans_kernel, dim3(N_), dim3(N_), 0, stream, fw, fwTb);
  hipLaunchKernelGGL(fused_kernel, dim3(B_ * T_), dim3(512), 0, stream,
                     x, entry, job, (const unsigned short*)fwTb, (float*)d_out);
}